// Round 4
// baseline (1939.125 us; speedup 1.0000x reference)
//
#include <hip/hip_runtime.h>

#define BATCH 32
#define SEQT 1000
#define INSZ 4
#define HID 2048
#define NOISE_STD 0.05f
#define ALPHA 0.2f
#define ONE_M_ALPHA (1.0f - ALPHA)

#define NTHREADS 64        // ONE wave per sequence: no barriers, no LDS, no cross-wave
#define NPAIR 16           // EPT 32 / 2
#define NLD 8              // float4 noise loads per step (32 floats/lane)

typedef float v2f __attribute__((ext_vector_type(2)));

// ---- forced VOP3P packed-f32 math ----
__device__ __forceinline__ v2f pk_fma(v2f a, v2f b, v2f c) {
    v2f d; asm("v_pk_fma_f32 %0, %1, %2, %3" : "=v"(d) : "v"(a), "v"(b), "v"(c)); return d;
}
__device__ __forceinline__ v2f pk_mul(v2f a, v2f b) {
    v2f d; asm("v_pk_mul_f32 %0, %1, %2" : "=v"(d) : "v"(a), "v"(b)); return d;
}
__device__ __forceinline__ v2f pk_add(v2f a, v2f b) {
    v2f d; asm("v_pk_add_f32 %0, %1, %2" : "=v"(d) : "v"(a), "v"(b)); return d;
}
#define C2(v) (v2f{(v), (v)})

// ---- fused DPP reductions (quad-interleaved: 4 indep chains -> no hazard bubbles)
// totals valid in lane 63 of the wave.
__device__ __forceinline__ void tree64_quad(float& a, float& b, float& c, float& d) {
    asm("s_nop 1\n\t"
        "v_add_f32_dpp %0, %0, %0 row_shr:1 row_mask:0xf bank_mask:0xf bound_ctrl:0\n\t"
        "v_add_f32_dpp %1, %1, %1 row_shr:1 row_mask:0xf bank_mask:0xf bound_ctrl:0\n\t"
        "v_add_f32_dpp %2, %2, %2 row_shr:1 row_mask:0xf bank_mask:0xf bound_ctrl:0\n\t"
        "v_add_f32_dpp %3, %3, %3 row_shr:1 row_mask:0xf bank_mask:0xf bound_ctrl:0\n\t"
        "v_add_f32_dpp %0, %0, %0 row_shr:2 row_mask:0xf bank_mask:0xf bound_ctrl:0\n\t"
        "v_add_f32_dpp %1, %1, %1 row_shr:2 row_mask:0xf bank_mask:0xf bound_ctrl:0\n\t"
        "v_add_f32_dpp %2, %2, %2 row_shr:2 row_mask:0xf bank_mask:0xf bound_ctrl:0\n\t"
        "v_add_f32_dpp %3, %3, %3 row_shr:2 row_mask:0xf bank_mask:0xf bound_ctrl:0\n\t"
        "v_add_f32_dpp %0, %0, %0 row_shr:4 row_mask:0xf bank_mask:0xf bound_ctrl:0\n\t"
        "v_add_f32_dpp %1, %1, %1 row_shr:4 row_mask:0xf bank_mask:0xf bound_ctrl:0\n\t"
        "v_add_f32_dpp %2, %2, %2 row_shr:4 row_mask:0xf bank_mask:0xf bound_ctrl:0\n\t"
        "v_add_f32_dpp %3, %3, %3 row_shr:4 row_mask:0xf bank_mask:0xf bound_ctrl:0\n\t"
        "v_add_f32_dpp %0, %0, %0 row_shr:8 row_mask:0xf bank_mask:0xf bound_ctrl:0\n\t"
        "v_add_f32_dpp %1, %1, %1 row_shr:8 row_mask:0xf bank_mask:0xf bound_ctrl:0\n\t"
        "v_add_f32_dpp %2, %2, %2 row_shr:8 row_mask:0xf bank_mask:0xf bound_ctrl:0\n\t"
        "v_add_f32_dpp %3, %3, %3 row_shr:8 row_mask:0xf bank_mask:0xf bound_ctrl:0\n\t"
        "v_add_f32_dpp %0, %0, %0 row_bcast:15 row_mask:0xf bank_mask:0xf bound_ctrl:0\n\t"
        "v_add_f32_dpp %1, %1, %1 row_bcast:15 row_mask:0xf bank_mask:0xf bound_ctrl:0\n\t"
        "v_add_f32_dpp %2, %2, %2 row_bcast:15 row_mask:0xf bank_mask:0xf bound_ctrl:0\n\t"
        "v_add_f32_dpp %3, %3, %3 row_bcast:15 row_mask:0xf bank_mask:0xf bound_ctrl:0\n\t"
        "v_add_f32_dpp %0, %0, %0 row_bcast:31 row_mask:0xf bank_mask:0xf bound_ctrl:0\n\t"
        "v_add_f32_dpp %1, %1, %1 row_bcast:31 row_mask:0xf bank_mask:0xf bound_ctrl:0\n\t"
        "v_add_f32_dpp %2, %2, %2 row_bcast:31 row_mask:0xf bank_mask:0xf bound_ctrl:0\n\t"
        "v_add_f32_dpp %3, %3, %3 row_bcast:31 row_mask:0xf bank_mask:0xf bound_ctrl:0"
        : "+v"(a), "+v"(b), "+v"(c), "+v"(d));
}

__device__ __forceinline__ void tree64_pair(float& a, float& b) {
    asm("s_nop 1\n\t"
        "v_add_f32_dpp %0, %0, %0 row_shr:1 row_mask:0xf bank_mask:0xf bound_ctrl:0\n\t"
        "v_add_f32_dpp %1, %1, %1 row_shr:1 row_mask:0xf bank_mask:0xf bound_ctrl:0\n\t"
        "v_add_f32_dpp %0, %0, %0 row_shr:2 row_mask:0xf bank_mask:0xf bound_ctrl:0\n\t"
        "v_add_f32_dpp %1, %1, %1 row_shr:2 row_mask:0xf bank_mask:0xf bound_ctrl:0\n\t"
        "v_add_f32_dpp %0, %0, %0 row_shr:4 row_mask:0xf bank_mask:0xf bound_ctrl:0\n\t"
        "v_add_f32_dpp %1, %1, %1 row_shr:4 row_mask:0xf bank_mask:0xf bound_ctrl:0\n\t"
        "v_add_f32_dpp %0, %0, %0 row_shr:8 row_mask:0xf bank_mask:0xf bound_ctrl:0\n\t"
        "v_add_f32_dpp %1, %1, %1 row_shr:8 row_mask:0xf bank_mask:0xf bound_ctrl:0\n\t"
        "v_add_f32_dpp %0, %0, %0 row_bcast:15 row_mask:0xf bank_mask:0xf bound_ctrl:0\n\t"
        "v_add_f32_dpp %1, %1, %1 row_bcast:15 row_mask:0xf bank_mask:0xf bound_ctrl:0\n\t"
        "v_add_f32_dpp %0, %0, %0 row_bcast:31 row_mask:0xf bank_mask:0xf bound_ctrl:0\n\t"
        "v_add_f32_dpp %1, %1, %1 row_bcast:31 row_mask:0xf bank_mask:0xf bound_ctrl:0"
        : "+v"(a), "+v"(b));
}

// tanh via Pade[5/4] + clamp (unchanged math)
__device__ __forceinline__ v2f pade_tanh(v2f x) {
    const v2f x2  = pk_mul(x, x);
    const v2f num = pk_mul(x, pk_fma(x2, pk_add(x2, C2(105.0f)), C2(945.0f)));
    const v2f den = pk_fma(x2, pk_fma(x2, C2(15.0f), C2(420.0f)), C2(945.0f));
    v2f r;
    r.x = num.x * __builtin_amdgcn_rcpf(den.x);
    r.y = num.y * __builtin_amdgcn_rcpf(den.y);
    r.x = fminf(fmaxf(r.x, -1.0f), 1.0f);
    r.y = fminf(fmaxf(r.y, -1.0f), 1.0f);
    return r;
}

__device__ __forceinline__ float pade_tanh_s(float x) {
    const float x2 = x * x;
    const float num = x * fmaf(x2, x2 + 105.0f, 945.0f);
    const float den = fmaf(x2, fmaf(x2, 15.0f, 420.0f), 945.0f);
    float r = num * __builtin_amdgcn_rcpf(den);
    return fminf(fmaxf(r, -1.0f), 1.0f);
}

__device__ __forceinline__ float readlane63(float x) {
    return __int_as_float(__builtin_amdgcn_readlane(__float_as_int(x), 63));
}

__global__ __launch_bounds__(NTHREADS, 1)   // allow full 512-VGPR budget
void rnn_kernel(const float* __restrict__ input,
                const float* __restrict__ noise,
                const float* __restrict__ wi_w,
                const float* __restrict__ m_w,
                const float* __restrict__ n_w,
                const float* __restrict__ wo_w,
                const float* __restrict__ wi_b,
                const float* __restrict__ m_b,
                const float* __restrict__ n_b,
                const float* __restrict__ h0_w,
                const float* __restrict__ gb,
                const float* __restrict__ sup,
                float* __restrict__ out)
{
    const int b    = blockIdx.x;
    const int lane = threadIdx.x;   // 0..63, one wave

    // ---- one-time proxy params
    // ownership: h = k*256 + lane*4 + e  (k=0..7, e=0..3) -> coalesced noise loads
    // pair index pi = 2k + (e>>1), component pc = e&1
    v2f wiA[INSZ][NPAIR];
    v2f mA0v[NPAIR], mA1v[NPAIR], n0v[NPAIR], n1v[NPAIR], wo0v[NPAIR], wo1v[NPAIR], hv[NPAIR];
    v2f q0 = {0.f, 0.f}, q1 = q0, q2 = q0, q3 = q0;

    #pragma unroll
    for (int k = 0; k < NLD; ++k) {
        #pragma unroll
        for (int e = 0; e < 4; ++e) {
            const int h = k * 256 + lane * 4 + e;
            const int pi = 2 * k + (e >> 1), pc = e & 1;
            float gv[8];
            #pragma unroll
            for (int g = 0; g < 8; ++g) gv[g] = gb[g * HID + h];
            const float s0 = sup[h];
            const float s1 = sup[HID + h];

            auto mix = [&](const float* w) -> float {
                float a0 = 0.f, a1 = 0.f;
                #pragma unroll
                for (int g = 0; g < 8; ++g) { a0 += w[g] * gv[g]; a1 += w[8 + g] * gv[g]; }
                return s0 * a0 + s1 * a1;
            };

            #pragma unroll
            for (int i = 0; i < INSZ; ++i)
                wiA[i][pi][pc] = ALPHA * (mix(wi_w + i * 16) + wi_b[i * 2 + 0] * s0 + wi_b[i * 2 + 1] * s1);
            mA0v[pi][pc] = ALPHA * (mix(m_w)      + m_b[0] * s0 + m_b[1] * s1);
            mA1v[pi][pc] = ALPHA * (mix(m_w + 16) + m_b[2] * s0 + m_b[3] * s1);
            const float n0 = mix(n_w)      + n_b[0] * s0 + n_b[1] * s1;
            const float n1 = mix(n_w + 16) + n_b[2] * s0 + n_b[3] * s1;
            const float w0 = mix(wo_w);
            const float w1 = mix(wo_w + 16);
            n0v[pi][pc] = n0;  n1v[pi][pc] = n1;
            wo0v[pi][pc] = w0; wo1v[pi][pc] = w1;
            {
                float a0 = 0.f, a1 = 0.f;
                #pragma unroll
                for (int g = 0; g < 8; ++g) { a0 += h0_w[g] * gv[g]; a1 += h0_w[8 + g] * gv[g]; }
                const float h0v = s0 * a0 + s1 * a1;
                hv[pi][pc] = h0v;
                const float r = pade_tanh_s(h0v);
                q0[pc] += r * n0;  q1[pc] += r * n1;
                q2[pc] += r * w0;  q3[pc] += r * w1;
            }
        }
    }

    // noise: 8 coalesced float4 per step (1 KB per load instr); 2-step double buffer
    const float4* nP4 = reinterpret_cast<const float4*>(noise + (size_t)b * SEQT * HID) + lane;
    float4 nbA[NLD], nbB[NLD];
    #pragma unroll
    for (int k = 0; k < NLD; ++k) nbA[k] = nP4[(size_t)0 * 512 + k * 64];
    #pragma unroll
    for (int k = 0; k < NLD; ++k) nbB[k] = nP4[(size_t)1 * 512 + k * 64];

    // input rows: uniform 16B global loads (L2-resident), 2-step double buffer
    const float4* inRow4 = reinterpret_cast<const float4*>(input + (size_t)b * SEQT * INSZ);
    float4 inA = inRow4[0];
    float4 inB = inRow4[1];

    float* outRow = out + (size_t)b * SEQT * 2;

    const v2f cNS  = C2(NOISE_STD);
    const v2f cOMA = C2(ONE_M_ALPHA);

    auto do_step = [&](int t, float4* nb, float4& invReg) {
        // ---- in-wave reduction of (y0,y1,o0,o1); totals land in lane 63
        float w0 = q0.x + q0.y;
        float w1 = q1.x + q1.y;
        float oz = q2.x + q2.y;
        float ow = q3.x + q3.y;
        tree64_quad(w0, w1, oz, ow);

        // broadcast y via readlane (uniform SGPR values)
        const float y0 = readlane63(w0);
        const float y1 = readlane63(w1);

        // output row t-1 (= wo . r^{(t)} at entry state), straight from lane 63
        if (t >= 1 && lane == 63)
            *reinterpret_cast<float2*>(outRow + (t - 1) * 2) = make_float2(oz, ow);

        // ---- phase A: consume noise buffer + input row
        const float4 inv = invReg;
        const v2f bx = {inv.x, inv.x}, by = {inv.y, inv.y};
        const v2f bz = {inv.z, inv.z}, bw = {inv.w, inv.w};
        v2f acc[NPAIR];
        #pragma unroll
        for (int k = 0; k < NLD; ++k) {
            const float4 nv = nb[k];
            const v2f nlo = {nv.x, nv.y}, nhi = {nv.z, nv.w};
            v2f a0 = pk_mul(wiA[0][2 * k], bx);
            v2f a1 = pk_mul(wiA[0][2 * k + 1], bx);
            a0 = pk_fma(wiA[1][2 * k],     by, a0);
            a1 = pk_fma(wiA[1][2 * k + 1], by, a1);
            a0 = pk_fma(wiA[2][2 * k],     bz, a0);
            a1 = pk_fma(wiA[2][2 * k + 1], bz, a1);
            a0 = pk_fma(wiA[3][2 * k],     bw, a0);
            a1 = pk_fma(wiA[3][2 * k + 1], bw, a1);
            a0 = pk_fma(nlo, cNS, a0);
            a1 = pk_fma(nhi, cNS, a1);
            a0 = pk_fma(hv[2 * k],     cOMA, a0);
            a1 = pk_fma(hv[2 * k + 1], cOMA, a1);
            acc[2 * k] = a0;
            acc[2 * k + 1] = a1;
        }

        // ---- prefetch t+2 into the just-consumed buffer (in flight ~2 steps)
        const int tpre = (t + 2 < SEQT) ? (t + 2) : (SEQT - 1);
        #pragma unroll
        for (int k = 0; k < NLD; ++k) nb[k] = nP4[(size_t)tpre * 512 + k * 64];
        invReg = inRow4[tpre];

        // ---- phase C: finish update + next partials
        const v2f y0p = {y0, y0}, y1p = {y1, y1};
        v2f r[NPAIR];
        #pragma unroll
        for (int p = 0; p < NPAIR; ++p) {
            v2f h2 = pk_fma(mA1v[p], y1p, acc[p]);
            h2 = pk_fma(mA0v[p], y0p, h2);
            hv[p] = h2;
            r[p] = pade_tanh(h2);
        }
        q0 = pk_mul(r[0], n0v[0]);  q1 = pk_mul(r[0], n1v[0]);
        q2 = pk_mul(r[0], wo0v[0]); q3 = pk_mul(r[0], wo1v[0]);
        #pragma unroll
        for (int p = 1; p < NPAIR; ++p) {
            q0 = pk_fma(r[p], n0v[p],  q0);
            q1 = pk_fma(r[p], n1v[p],  q1);
            q2 = pk_fma(r[p], wo0v[p], q2);
            q3 = pk_fma(r[p], wo1v[p], q3);
        }
    };

    for (int t = 0; t < SEQT; t += 2) {
        do_step(t,     nbA, inA);
        do_step(t + 1, nbB, inB);
    }

    // epilogue: row 999 = wo . r^{(1000)} from final q2,q3
    {
        float a9 = q2.x + q2.y;
        float b9 = q3.x + q3.y;
        tree64_pair(a9, b9);
        if (lane == 63)
            *reinterpret_cast<float2*>(outRow + 999 * 2) = make_float2(a9, b9);
    }
}

extern "C" void kernel_launch(void* const* d_in, const int* in_sizes, int n_in,
                              void* d_out, int out_size, void* d_ws, size_t ws_size,
                              hipStream_t stream) {
    const float* input = (const float*)d_in[0];
    const float* noise = (const float*)d_in[1];
    const float* wi_w  = (const float*)d_in[2];
    const float* m_w   = (const float*)d_in[3];
    const float* n_w   = (const float*)d_in[4];
    const float* wo_w  = (const float*)d_in[5];
    const float* wi_b  = (const float*)d_in[6];
    const float* m_b   = (const float*)d_in[7];
    const float* n_b   = (const float*)d_in[8];
    const float* h0_w  = (const float*)d_in[9];
    const float* gb    = (const float*)d_in[10];
    const float* sup   = (const float*)d_in[11];
    float* out = (float*)d_out;

    rnn_kernel<<<dim3(BATCH), dim3(NTHREADS), 0, stream>>>(
        input, noise, wi_w, m_w, n_w, wo_w, wi_b, m_b, n_b, h0_w, gb, sup, out);
}